// Round 21
// baseline (590.567 us; speedup 1.0000x reference)
//
#include <hip/hip_runtime.h>
#include <hip/hip_bf16.h>
#include <hip/hip_cooperative_groups.h>
#include <math.h>

namespace cg = cooperative_groups;

namespace {

constexpr int B  = 4;
constexpr int N  = 2048;
constexpr int F0 = 6;
constexpr int F  = 64;
constexpr int DK = 16;
constexpr float EPS = 1e-5f;
constexpr int MT   = N / 64;  // m-tiles
constexpr int NCH  = 4;       // n-chunks

typedef float fx4 __attribute__((ext_vector_type(4)));
typedef __attribute__((ext_vector_type(8)))  short bf16x8;
typedef __attribute__((ext_vector_type(4)))  short bf16x4;
typedef __attribute__((ext_vector_type(16))) float f32x16;

__device__ inline short f2bf(float x, float* xr) {
  __hip_bfloat16 h = __float2bfloat16(x);
  *xr = __bfloat162float(h);
  short s; __builtin_memcpy(&s, &h, 2);
  return s;
}
__device__ inline short f2bf(float x) {
  __hip_bfloat16 h = __float2bfloat16(x);
  short s; __builtin_memcpy(&s, &h, 2);
  return s;
}
__device__ inline float bf2f(short s) {
  unsigned int u = ((unsigned int)(unsigned short)s) << 16;
  float f; __builtin_memcpy(&f, &u, 4);
  return f;
}

struct WXShared {
  float xS[64][65];
  __align__(16) float wT[64][136];
  float mnS[64], rsS[64];
  float sp[4][64];
};
struct AdjShared {
  __align__(16) short adjT[2][64][68];
  __align__(16) short vS[2][64][68];
  float sqmS[64];
  float degS[2][64];
};
struct EpShared { float r1[4], r2[4]; };

constexpr size_t SMEM_SZ =
    sizeof(WXShared) > sizeof(AdjShared) ? sizeof(WXShared) : sizeof(AdjShared);

// ---------------- wx phase: weight-folding GEMMs -> bf16 operands ----------------
template<int FIN, bool NORM, bool XBF>
__device__ __forceinline__ void wx_phase(int z, int b, int n0, char* sm,
                                         const float* Xf, const short* Xb,
                                         const float* sigma,
                                         const float* ssum, const float* ssq,
                                         const float* Wc, const float* Wr,
                                         const float* Ap,
                                         short* Tq, short* Tbf,
                                         short* projT, float* sqnb) {
  WXShared& S = *reinterpret_cast<WXShared*>(sm);
  int t = threadIdx.x, n = t & 63, og = t >> 6;
  for (int e = t; e < FIN * 64; e += 256) {
    int f = e >> 6, nn = e & 63;
    float v = XBF ? bf2f(Xb[((size_t)b * FIN + f) * N + n0 + nn])
                  : Xf[((size_t)b * FIN + f) * N + n0 + nn];
    S.xS[nn][f] = v;
  }
  bool l0proj = (z == 2 && Ap == nullptr);
  if (z == 0) {
    for (int e = t; e < 64 * FIN; e += 256) {
      int o = e / FIN, f = e - o * FIN;
      S.wT[f][o] = Wc[(size_t)o * 2 * FIN + f];
      S.wT[f][64 + o] = Wr[(size_t)o * FIN + f];
    }
  } else if (z == 1) {
    for (int e = t; e < 64 * FIN; e += 256) {
      int o = e / FIN, f = e - o * FIN;
      S.wT[f][o] = Wc[(size_t)o * 2 * FIN + FIN + f];
    }
  } else if (!l0proj) {
    for (int e = t; e < DK * FIN; e += 256) {
      int o = e / FIN, f = e - o * FIN;
      S.wT[f][o] = Ap[(size_t)o * FIN + f];
    }
  }
  if (NORM && z < 2 && t < 64) {
    int row = b * FIN + t;
    float Ssum = ssum[row];
    float Q = ssq[row];
    float mn = Ssum / (float)N;
    S.mnS[t] = mn;
    S.rsS[t] = rsqrtf(Q / (float)N - mn * mn + EPS);
  }
  __syncthreads();
  if (z == 0) {
    float c1[16] = {}, c2[16] = {};
#pragma unroll 4
    for (int f = 0; f < FIN; ++f) {
      float x = S.xS[n][f];
      if (NORM) x = (x - S.mnS[f]) * S.rsS[f];
      fx4 w0 = *(const fx4*)&S.wT[f][og * 16 + 0];
      fx4 w1 = *(const fx4*)&S.wT[f][og * 16 + 4];
      fx4 w2 = *(const fx4*)&S.wT[f][og * 16 + 8];
      fx4 w3 = *(const fx4*)&S.wT[f][og * 16 + 12];
      fx4 u0 = *(const fx4*)&S.wT[f][64 + og * 16 + 0];
      fx4 u1 = *(const fx4*)&S.wT[f][64 + og * 16 + 4];
      fx4 u2 = *(const fx4*)&S.wT[f][64 + og * 16 + 8];
      fx4 u3 = *(const fx4*)&S.wT[f][64 + og * 16 + 12];
#pragma unroll
      for (int k = 0; k < 4; ++k) {
        c1[k + 0]  = fmaf(w0[k], x, c1[k + 0]);
        c1[k + 4]  = fmaf(w1[k], x, c1[k + 4]);
        c1[k + 8]  = fmaf(w2[k], x, c1[k + 8]);
        c1[k + 12] = fmaf(w3[k], x, c1[k + 12]);
        c2[k + 0]  = fmaf(u0[k], x, c2[k + 0]);
        c2[k + 4]  = fmaf(u1[k], x, c2[k + 4]);
        c2[k + 8]  = fmaf(u2[k], x, c2[k + 8]);
        c2[k + 12] = fmaf(u3[k], x, c2[k + 12]);
      }
    }
#pragma unroll
    for (int k = 0; k < 16; ++k) {
      Tq[(((size_t)b * 2 + 0) * 64 + og * 16 + k) * N + n0 + n] = f2bf(c1[k]);
      Tq[(((size_t)b * 2 + 1) * 64 + og * 16 + k) * N + n0 + n] = f2bf(c2[k]);
    }
  } else if (z == 1) {
    float cacc[16] = {};
#pragma unroll 4
    for (int f = 0; f < FIN; ++f) {
      float x = S.xS[n][f];
      if (NORM) x = (x - S.mnS[f]) * S.rsS[f];
      fx4 w0 = *(const fx4*)&S.wT[f][og * 16 + 0];
      fx4 w1 = *(const fx4*)&S.wT[f][og * 16 + 4];
      fx4 w2 = *(const fx4*)&S.wT[f][og * 16 + 8];
      fx4 w3 = *(const fx4*)&S.wT[f][og * 16 + 12];
#pragma unroll
      for (int k = 0; k < 4; ++k) {
        cacc[k + 0]  = fmaf(w0[k], x, cacc[k + 0]);
        cacc[k + 4]  = fmaf(w1[k], x, cacc[k + 4]);
        cacc[k + 8]  = fmaf(w2[k], x, cacc[k + 8]);
        cacc[k + 12] = fmaf(w3[k], x, cacc[k + 12]);
      }
    }
#pragma unroll
    for (int k = 0; k < 16; ++k)
      Tbf[((size_t)b * 64 + og * 16 + k) * N + n0 + n] = f2bf(cacc[k]);
  } else {
    float r[4];
    bf16x4 hv;
    if (Ap != nullptr) {
      float cacc[4] = {};
#pragma unroll 4
      for (int f = 0; f < FIN; ++f) {
        float x = S.xS[n][f];
        fx4 w0 = *(const fx4*)&S.wT[f][og * 4];
#pragma unroll
        for (int k = 0; k < 4; ++k) cacc[k] = fmaf(w0[k], x, cacc[k]);
      }
#pragma unroll
      for (int k = 0; k < 4; ++k) hv[k] = f2bf(cacc[k], &r[k]);
    } else {
      float inv = 1.f / sigma[0];
#pragma unroll
      for (int k = 0; k < 4; ++k) {
        int d = og * 4 + k;
        float v = (d < F0) ? S.xS[n][d] * inv : 0.f;
        hv[k] = f2bf(v, &r[k]);
      }
    }
    *(bf16x4*)&projT[((size_t)b * N + n0 + n) * DK + og * 4] = hv;
    float s = 0.f;
#pragma unroll
    for (int k = 0; k < 4; ++k) s = fmaf(r[k], r[k], s);
    S.sp[og][n] = s;
    __syncthreads();
    if (t < 64)
      sqnb[(size_t)b * N + n0 + t] = S.sp[0][t] + S.sp[1][t] + S.sp[2][t] + S.sp[3][t];
  }
}

// ---------------- adjacency+deg+PV phase (bf16 MFMA, prefetched) ----------------
__device__ __forceinline__ void adj_phase(int i, char* sm,
                                          const short* projT, const float* sqnb,
                                          const short* Tbf,
                                          short* pdmsg, float* pdeg) {
  AdjShared& A = *reinterpret_cast<AdjShared*>(sm);
  constexpr int NCb = N / NCH;
  constexpr int CPX = NCH * B / 8;
  int xcd = i & 7;
  int j = i >> 3;
  int lc = j / MT;
  int mtile = j - lc * MT;
  int combo = xcd * CPX + lc;
  int ch = combo >> 2;
  int b  = combo & 3;
  int M0 = mtile * 64;
  int n0 = ch * NCb;

  int t = threadIdx.x;
  int w = t >> 6, l = t & 63;
  int l31 = l & 31, lh = l >> 5;
  int mq = w & 1, nq = w >> 1;
  int fq = w & 1, mq2 = w >> 1;

  const short* pbT = projT + (size_t)b * N * DK;
  const short* vb = Tbf + (size_t)b * F * N;
  const float* sq = sqnb + (size_t)b * N;

  int am = l31 + 32 * mq;
  bf16x8 afrag = *(const bf16x8*)&pbT[(size_t)(M0 + am) * DK + lh * 8];
  if (t < 64) A.sqmS[t] = sq[M0 + t];
  __syncthreads();
  float sqmr[16];
#pragma unroll
  for (int r = 0; r < 16; ++r)
    sqmr[r] = A.sqmS[(r & 3) + 8 * (r >> 2) + 4 * lh + 32 * mq];

  f32x16 acc;
#pragma unroll
  for (int r = 0; r < 16; ++r) acc[r] = 0.f;
  float pdm[16];
#pragma unroll
  for (int r = 0; r < 16; ++r) pdm[r] = 0.f;

  int bn = l31 + 32 * nq;
  int fV = t >> 2, nb16 = (t & 3) * 16;
  bf16x8 bfrag = *(const bf16x8*)&pbT[(size_t)(n0 + bn) * DK + lh * 8];
  float sqn_v = sq[n0 + bn];
  bf16x4 vreg[4];
#pragma unroll
  for (int jj = 0; jj < 4; ++jj)
    vreg[jj] = *(const bf16x4*)&vb[(size_t)fV * N + n0 + nb16 + 4 * jj];

  int buf = 0;
  for (int nt = 0; nt < NCb; nt += 64) {
#pragma unroll
    for (int jj = 0; jj < 4; ++jj)
      *(bf16x4*)&A.vS[buf][fV][nb16 + 4 * jj] = vreg[jj];
    f32x16 gz;
#pragma unroll
    for (int r = 0; r < 16; ++r) gz[r] = 0.f;
    f32x16 g = __builtin_amdgcn_mfma_f32_32x32x16_bf16(afrag, bfrag, gz, 0, 0, 0);
#pragma unroll
    for (int r = 0; r < 16; ++r) {
      int m = (r & 3) + 8 * (r >> 2) + 4 * lh + 32 * mq;
      float dist = fmaxf(sqmr[r] + sqn_v - 2.f * g[r], 0.f);
      float a = __expf(-dist);
      pdm[r] += a;
      A.adjT[buf][m][bn] = f2bf(a);
    }
    if (nt + 64 < NCb) {
      bfrag = *(const bf16x8*)&pbT[(size_t)(n0 + nt + 64 + bn) * DK + lh * 8];
      sqn_v = sq[n0 + nt + 64 + bn];
#pragma unroll
      for (int jj = 0; jj < 4; ++jj)
        vreg[jj] = *(const bf16x4*)&vb[(size_t)fV * N + n0 + nt + 64 + nb16 + 4 * jj];
    }
    __syncthreads();
#pragma unroll
    for (int kk = 0; kk < 4; ++kk) {
      int nb = kk * 16 + lh * 8;
      int fA = l31 + 32 * fq;
      int mB = l31 + 32 * mq2;
      bf16x4 alo = *(const bf16x4*)&A.vS[buf][fA][nb];
      bf16x4 ahi = *(const bf16x4*)&A.vS[buf][fA][nb + 4];
      bf16x4 blo = *(const bf16x4*)&A.adjT[buf][mB][nb];
      bf16x4 bhi = *(const bf16x4*)&A.adjT[buf][mB][nb + 4];
      bf16x8 af2, bf2;
#pragma unroll
      for (int i2 = 0; i2 < 4; ++i2) {
        af2[i2] = alo[i2]; af2[i2 + 4] = ahi[i2];
        bf2[i2] = blo[i2]; bf2[i2 + 4] = bhi[i2];
      }
      acc = __builtin_amdgcn_mfma_f32_32x32x16_bf16(af2, bf2, acc, 0, 0, 0);
    }
    buf ^= 1;
  }
#pragma unroll
  for (int r = 0; r < 16; ++r) {
    pdm[r] += __shfl_xor(pdm[r], 1);
    pdm[r] += __shfl_xor(pdm[r], 2);
    pdm[r] += __shfl_xor(pdm[r], 4);
    pdm[r] += __shfl_xor(pdm[r], 8);
    pdm[r] += __shfl_xor(pdm[r], 16);
  }
  if (l31 == 0) {
#pragma unroll
    for (int r = 0; r < 16; ++r)
      A.degS[nq][(r & 3) + 8 * (r >> 2) + 4 * lh + 32 * mq] = pdm[r];
  }
  __syncthreads();
  if (t < 64) {
    float s = A.degS[0][t] + A.degS[1][t];
    __builtin_nontemporal_store(s, &pdeg[(size_t)combo * N + M0 + t]);
  }
  short* pdm_g = pdmsg + (size_t)combo * F * N;
  int m_out = l31 + 32 * mq2;
#pragma unroll
  for (int r = 0; r < 16; ++r) {
    int f_r = (r & 3) + 8 * (r >> 2) + 4 * lh + 32 * fq;
    __builtin_nontemporal_store(f2bf(acc[r]), &pdm_g[(size_t)f_r * N + M0 + m_out]);
  }
}

// ---------------- ep phase: combine + epilogue + full-row stats ----------------
__device__ __forceinline__ void ep_phase(int row, char* sm,
                                         const short* pdmsg, const float* pdeg,
                                         const short* Tq,
                                         const float* bias, const float* bres,
                                         short* out, float* ssum, float* ssq) {
  EpShared& E = *reinterpret_cast<EpShared*>(sm);
  int o = row & 63, b = row >> 6;
  int t = threadIdx.x;
  float ps = 0.f, pq = 0.f;
  float bi = bias[o], br = bres[o];
#pragma unroll
  for (int h = 0; h < 2; ++h) {
    int c4 = t + h * 256;
    fx4 dm = {0.f, 0.f, 0.f, 0.f};
    fx4 dg = {0.f, 0.f, 0.f, 0.f};
#pragma unroll
    for (int c = 0; c < NCH; ++c) {
      bf16x4 pv = __builtin_nontemporal_load(
          &((const bf16x4*)pdmsg)[(((size_t)c * B + b) * 64 + o) * 512 + c4]);
#pragma unroll
      for (int j = 0; j < 4; ++j) dm[j] += bf2f(pv[j]);
      dg += ((const fx4*)pdeg)[((size_t)c * B + b) * 512 + c4];
    }
    bf16x4 t0v = ((const bf16x4*)Tq)[(((size_t)b * 2 + 0) * 64 + o) * 512 + c4];
    bf16x4 t2v = ((const bf16x4*)Tq)[(((size_t)b * 2 + 1) * 64 + o) * 512 + c4];
    bf16x4 ob;
#pragma unroll
    for (int j = 0; j < 4; ++j) {
      float v = fmaxf(dm[j] + bf2f(t0v[j]) * dg[j] + bi, 0.f) + bf2f(t2v[j]) + br;
      ps += v;
      pq = fmaf(v, v, pq);
      ob[j] = f2bf(v);
    }
    ((bf16x4*)out)[((size_t)b * 64 + o) * 512 + c4] = ob;
  }
#pragma unroll
  for (int off = 1; off < 64; off <<= 1) {
    ps += __shfl_xor(ps, off);
    pq += __shfl_xor(pq, off);
  }
  if ((t & 63) == 0) { E.r1[t >> 6] = ps; E.r2[t >> 6] = pq; }
  __syncthreads();
  if (t == 0) {
    ssum[row] = E.r1[0] + E.r1[1] + E.r1[2] + E.r1[3];
    ssq[row]  = E.r2[0] + E.r2[1] + E.r2[2] + E.r2[3];
  }
}

// ---------------- readout phase ----------------
__device__ __forceinline__ void readout_phase(const float* ssum, const float* fw,
                                              const float* fb, float* out) {
  int t = threadIdx.x, b = t >> 6, l = t & 63;
  float po = ssum[b * 64 + l] / (float)N;
  float mn = po;
#pragma unroll
  for (int off = 1; off < 64; off <<= 1) mn += __shfl_xor(mn, off);
  mn *= (1.f / 64.f);
  float d = po - mn;
  float var = d * d;
#pragma unroll
  for (int off = 1; off < 64; off <<= 1) var += __shfl_xor(var, off);
  var *= (1.f / 64.f);
  float rs = rsqrtf(var + EPS);
  float lg = d * rs * fw[l];
#pragma unroll
  for (int off = 1; off < 64; off <<= 1) lg += __shfl_xor(lg, off);
  if (l == 0) out[b] = 1.f / (1.f + __expf(-(lg + fb[0])));
}

// ---------------- fused cooperative kernel ----------------
struct KP {
  const float *emb_in, *sigma, *fst_w, *fst_b, *fst_wres, *fst_bres;
  const float *adj_proj, *w, *bw, *wres, *bres, *fcl_w, *fcl_b;
  float* outF;
  float* pdeg;
  short* pdmsg;
  short* embA;
  short* embB;
  short* Tq;
  short* Tbf;
  short* projT;
  float* sqnb;
  float* ssum;
  float* ssq;
};

__global__ __launch_bounds__(256, 2) void k_fused(KP p) {
  __shared__ __align__(16) char sm[SMEM_SZ];
  cg::grid_group grid = cg::this_grid();
  int blk = blockIdx.x;

  // ---- layer 0 ----
  if (blk < 384) {
    int z = blk >> 7, r = blk & 127, b = r >> 5, n0 = (r & 31) << 6;
    wx_phase<F0, false, false>(z, b, n0, sm, p.emb_in, nullptr, p.sigma,
                               nullptr, nullptr, p.fst_w, p.fst_wres, nullptr,
                               p.Tq, p.Tbf, p.projT, p.sqnb);
  }
  grid.sync();
  adj_phase(blk, sm, p.projT, p.sqnb, p.Tbf, p.pdmsg, p.pdeg);
  grid.sync();
  if (blk < 256)
    ep_phase(blk, sm, p.pdmsg, p.pdeg, p.Tq, p.fst_b, p.fst_bres, p.embA,
             p.ssum, p.ssq);
  grid.sync();

  // ---- layers 1..2 ----
  const short* src = p.embA;
  short* dst = p.embB;
#pragma unroll 1
  for (int i = 0; i < 2; ++i) {
    if (blk < 384) {
      int z = blk >> 7, r = blk & 127, b = r >> 5, n0 = (r & 31) << 6;
      wx_phase<F, true, true>(z, b, n0, sm, nullptr, src, nullptr,
                              p.ssum, p.ssq, p.w + (size_t)i * F * 2 * F,
                              p.wres + (size_t)i * F * F,
                              p.adj_proj + (size_t)i * DK * F,
                              p.Tq, p.Tbf, p.projT, p.sqnb);
    }
    grid.sync();
    adj_phase(blk, sm, p.projT, p.sqnb, p.Tbf, p.pdmsg, p.pdeg);
    grid.sync();
    if (blk < 256)
      ep_phase(blk, sm, p.pdmsg, p.pdeg, p.Tq, p.bw + (size_t)i * F,
               p.bres + (size_t)i * F, dst, p.ssum, p.ssq);
    grid.sync();
    short* tmp = (short*)src;
    src = dst;
    dst = tmp;
  }

  if (blk == 0) readout_phase(p.ssum, p.fcl_w, p.fcl_b, p.outF);
}

// ---------------- standalone fallback kernels (R20 path, same device fns) ----------------
template<int FIN, bool NORM, bool XBF>
__global__ __launch_bounds__(256) void k_wx_s(const float* Xf, const short* Xb,
                                              const float* sigma,
                                              const float* ssum, const float* ssq,
                                              const float* Wc, const float* Wr,
                                              const float* Ap,
                                              short* Tq, short* Tbf,
                                              short* projT, float* sqnb) {
  __shared__ __align__(16) char sm[sizeof(WXShared)];
  wx_phase<FIN, NORM, XBF>(blockIdx.z, blockIdx.y, blockIdx.x * 64, sm,
                           Xf, Xb, sigma, ssum, ssq, Wc, Wr, Ap,
                           Tq, Tbf, projT, sqnb);
}

__global__ __launch_bounds__(256, 4) void k_adj_s(const short* projT,
                                                  const float* sqnb,
                                                  const short* Tbf,
                                                  short* pdmsg, float* pdeg) {
  __shared__ __align__(16) char sm[sizeof(AdjShared)];
  adj_phase(blockIdx.x, sm, projT, sqnb, Tbf, pdmsg, pdeg);
}

__global__ __launch_bounds__(256) void k_ep_s(const short* pdmsg, const float* pdeg,
                                              const short* Tq, const float* bias,
                                              const float* bres, short* out,
                                              float* ssum, float* ssq) {
  __shared__ __align__(16) char sm[sizeof(EpShared)];
  ep_phase(blockIdx.x, sm, pdmsg, pdeg, Tq, bias, bres, out, ssum, ssq);
}

__global__ __launch_bounds__(256) void k_ro_s(const float* ssum, const float* fw,
                                              const float* fb, float* out) {
  readout_phase(ssum, fw, fb, out);
}

}  // namespace

extern "C" void kernel_launch(void* const* d_in, const int* in_sizes, int n_in,
                              void* d_out, int out_size, void* d_ws, size_t ws_size,
                              hipStream_t stream) {
  const float* emb_in   = (const float*)d_in[0];
  const float* sigma    = (const float*)d_in[1];
  const float* fst_w    = (const float*)d_in[2];
  const float* fst_b    = (const float*)d_in[3];
  const float* fst_wres = (const float*)d_in[4];
  const float* fst_bres = (const float*)d_in[5];
  const float* adj_proj = (const float*)d_in[6];
  const float* w        = (const float*)d_in[7];
  const float* bw       = (const float*)d_in[8];
  const float* wres     = (const float*)d_in[9];
  const float* bres     = (const float*)d_in[10];
  const float* fcl_w    = (const float*)d_in[11];
  const float* fcl_b    = (const float*)d_in[12];

  float* ws = (float*)d_ws;
  float* pdeg  = ws;  ws += (size_t)NCH * B * N;
  short* pdmsg = (short*)ws;  ws += (size_t)NCH * B * F * N / 2;  // bf16
  short* embA  = (short*)ws;  ws += (size_t)B * F * N / 2;        // bf16
  short* embB  = (short*)ws;  ws += (size_t)B * F * N / 2;        // bf16
  short* Tq    = (short*)ws;  ws += (size_t)B * F * N;            // 2 slices bf16
  short* Tbf   = (short*)ws;  ws += (size_t)B * F * N / 2;
  short* projT = (short*)ws;  ws += (size_t)B * DK * N / 2;
  float* sqnb  = ws;  ws += (size_t)B * N;
  float* ssum  = ws;  ws += (size_t)B * F;
  float* ssq   = ws;  ws += (size_t)B * F;

  KP p;
  p.emb_in = emb_in; p.sigma = sigma; p.fst_w = fst_w; p.fst_b = fst_b;
  p.fst_wres = fst_wres; p.fst_bres = fst_bres; p.adj_proj = adj_proj;
  p.w = w; p.bw = bw; p.wres = wres; p.bres = bres;
  p.fcl_w = fcl_w; p.fcl_b = fcl_b; p.outF = (float*)d_out;
  p.pdeg = pdeg; p.pdmsg = pdmsg; p.embA = embA; p.embB = embB;
  p.Tq = Tq; p.Tbf = Tbf; p.projT = projT; p.sqnb = sqnb;
  p.ssum = ssum; p.ssq = ssq;

  void* kargs[] = {&p};
  hipError_t err = hipLaunchCooperativeKernel((const void*)k_fused, dim3(512),
                                              dim3(256), kargs, 0, stream);
  if (err == hipSuccess) return;

  // ---- fallback: verified R20 10-dispatch path ----
  constexpr int EPB = B * F;
  constexpr int AJB = MT * NCH * B;

  k_wx_s<F0, false, false><<<dim3(N / 64, B, 3), 256, 0, stream>>>(
      emb_in, nullptr, sigma, nullptr, nullptr, fst_w, fst_wres, nullptr,
      Tq, Tbf, projT, sqnb);
  k_adj_s<<<dim3(AJB), 256, 0, stream>>>(projT, sqnb, Tbf, pdmsg, pdeg);
  k_ep_s<<<dim3(EPB), 256, 0, stream>>>(pdmsg, pdeg, Tq, fst_b, fst_bres, embA,
                                        ssum, ssq);

  const short* src = embA;
  short* dst = embB;
  for (int i = 0; i < 2; ++i) {
    k_wx_s<F, true, true><<<dim3(N / 64, B, 3), 256, 0, stream>>>(
        nullptr, src, nullptr, ssum, ssq, w + (size_t)i * F * 2 * F,
        wres + (size_t)i * F * F, adj_proj + (size_t)i * DK * F,
        Tq, Tbf, projT, sqnb);
    k_adj_s<<<dim3(AJB), 256, 0, stream>>>(projT, sqnb, Tbf, pdmsg, pdeg);
    k_ep_s<<<dim3(EPB), 256, 0, stream>>>(pdmsg, pdeg, Tq, bw + (size_t)i * F,
                                          bres + (size_t)i * F, dst, ssum, ssq);
    short* tmp = (short*)src;
    src = dst;
    dst = tmp;
  }

  k_ro_s<<<dim3(1), 256, 0, stream>>>(ssum, fcl_w, fcl_b, (float*)d_out);
}

// Round 22
// 81.217 us; speedup vs baseline: 7.2715x; 7.2715x over previous
//
#include <hip/hip_runtime.h>
#include <hip/hip_bf16.h>
#include <math.h>

namespace {

constexpr int B  = 4;
constexpr int N  = 2048;
constexpr int F0 = 6;
constexpr int F  = 64;
constexpr int DK = 16;
constexpr float EPS = 1e-5f;
constexpr int MT   = N / 64;  // m-tiles
constexpr int NCH  = 4;       // n-chunks

typedef float fx4 __attribute__((ext_vector_type(4)));
typedef __attribute__((ext_vector_type(8)))  short bf16x8;
typedef __attribute__((ext_vector_type(4)))  short bf16x4;
typedef __attribute__((ext_vector_type(16))) float f32x16;

__device__ inline short f2bf(float x, float* xr) {
  __hip_bfloat16 h = __float2bfloat16(x);
  *xr = __bfloat162float(h);
  short s; __builtin_memcpy(&s, &h, 2);
  return s;
}
__device__ inline short f2bf(float x) {
  __hip_bfloat16 h = __float2bfloat16(x);
  short s; __builtin_memcpy(&s, &h, 2);
  return s;
}
__device__ inline float bf2f(short s) {
  unsigned int u = ((unsigned int)(unsigned short)s) << 16;
  float f; __builtin_memcpy(&f, &u, 4);
  return f;
}

// ---------------- weight-folding GEMMs -> bf16 operands ----------------
// z==0: Tq slice0 = bf16(W1·norm(X)) AND Tq slice1 = bf16(Wres·norm(X))  [merged]
// z==1: Tbf = bf16(W2·norm(X))
// z==2: projT = bf16(Ap·X) (B,N,DK) + sqnb  (layer 0: bf16(X/sigma), padded)
template<int FIN, bool NORM, bool XBF>
__global__ __launch_bounds__(256) void k_wx(const float* __restrict__ Xf,    // fp32 X (layer 0)
                                            const short* __restrict__ Xb,    // bf16 X (layers 1-2)
                                            const float* __restrict__ sigma, // layer0 only
                                            const float* __restrict__ ssum,  // (B*F) row sums
                                            const float* __restrict__ ssq,
                                            const float* __restrict__ Wc,    // (64,2*FIN)
                                            const float* __restrict__ Wr,    // (64,FIN)
                                            const float* __restrict__ Ap,    // (DK,FIN) or null
                                            short* __restrict__ Tq,          // (B,2,64,N) bf16
                                            short* __restrict__ Tbf,         // (B,64,N) bf16
                                            short* __restrict__ projT,       // (B,N,DK) bf16
                                            float* __restrict__ sqnb) {      // (B,N)
  int z = blockIdx.z, b = blockIdx.y, n0 = blockIdx.x * 64;
  int t = threadIdx.x, n = t & 63, og = t >> 6;
  __shared__ float xS[64][FIN + 1];
  __shared__ __align__(16) float wT[FIN][136];  // z0: [0..63]=W1, [64..127]=Wres
  __shared__ float mnS[64], rsS[64];
  __shared__ float sp[4][64];
  for (int e = t; e < FIN * 64; e += 256) {
    int f = e >> 6, nn = e & 63;
    float v = XBF ? bf2f(Xb[((size_t)b * FIN + f) * N + n0 + nn])
                  : Xf[((size_t)b * FIN + f) * N + n0 + nn];
    xS[nn][f] = v;
  }
  bool l0proj = (z == 2 && Ap == nullptr);
  if (z == 0) {
    for (int e = t; e < 64 * FIN; e += 256) {
      int o = e / FIN, f = e - o * FIN;
      wT[f][o] = Wc[(size_t)o * 2 * FIN + f];
      wT[f][64 + o] = Wr[(size_t)o * FIN + f];
    }
  } else if (z == 1) {
    for (int e = t; e < 64 * FIN; e += 256) {
      int o = e / FIN, f = e - o * FIN;
      wT[f][o] = Wc[(size_t)o * 2 * FIN + FIN + f];
    }
  } else if (!l0proj) {
    for (int e = t; e < DK * FIN; e += 256) {
      int o = e / FIN, f = e - o * FIN;
      wT[f][o] = Ap[(size_t)o * FIN + f];
    }
  }
  if (NORM && z < 2 && t < 64) {  // mean/rstd from ep full-row sums
    int row = b * FIN + t;
    float S = ssum[row];
    float Q = ssq[row];
    float mn = S / (float)N;
    mnS[t] = mn;
    rsS[t] = rsqrtf(Q / (float)N - mn * mn + EPS);
  }
  __syncthreads();
  if (z == 0) {
    float c1[16] = {}, c2[16] = {};
#pragma unroll 4
    for (int f = 0; f < FIN; ++f) {
      float x = xS[n][f];
      if (NORM) x = (x - mnS[f]) * rsS[f];
      fx4 w0 = *(const fx4*)&wT[f][og * 16 + 0];
      fx4 w1 = *(const fx4*)&wT[f][og * 16 + 4];
      fx4 w2 = *(const fx4*)&wT[f][og * 16 + 8];
      fx4 w3 = *(const fx4*)&wT[f][og * 16 + 12];
      fx4 u0 = *(const fx4*)&wT[f][64 + og * 16 + 0];
      fx4 u1 = *(const fx4*)&wT[f][64 + og * 16 + 4];
      fx4 u2 = *(const fx4*)&wT[f][64 + og * 16 + 8];
      fx4 u3 = *(const fx4*)&wT[f][64 + og * 16 + 12];
#pragma unroll
      for (int k = 0; k < 4; ++k) {
        c1[k + 0]  = fmaf(w0[k], x, c1[k + 0]);
        c1[k + 4]  = fmaf(w1[k], x, c1[k + 4]);
        c1[k + 8]  = fmaf(w2[k], x, c1[k + 8]);
        c1[k + 12] = fmaf(w3[k], x, c1[k + 12]);
        c2[k + 0]  = fmaf(u0[k], x, c2[k + 0]);
        c2[k + 4]  = fmaf(u1[k], x, c2[k + 4]);
        c2[k + 8]  = fmaf(u2[k], x, c2[k + 8]);
        c2[k + 12] = fmaf(u3[k], x, c2[k + 12]);
      }
    }
#pragma unroll
    for (int k = 0; k < 16; ++k) {
      Tq[(((size_t)b * 2 + 0) * 64 + og * 16 + k) * N + n0 + n] = f2bf(c1[k]);
      Tq[(((size_t)b * 2 + 1) * 64 + og * 16 + k) * N + n0 + n] = f2bf(c2[k]);
    }
  } else if (z == 1) {
    float cacc[16] = {};
#pragma unroll 4
    for (int f = 0; f < FIN; ++f) {
      float x = xS[n][f];
      if (NORM) x = (x - mnS[f]) * rsS[f];
      fx4 w0 = *(const fx4*)&wT[f][og * 16 + 0];
      fx4 w1 = *(const fx4*)&wT[f][og * 16 + 4];
      fx4 w2 = *(const fx4*)&wT[f][og * 16 + 8];
      fx4 w3 = *(const fx4*)&wT[f][og * 16 + 12];
#pragma unroll
      for (int k = 0; k < 4; ++k) {
        cacc[k + 0]  = fmaf(w0[k], x, cacc[k + 0]);
        cacc[k + 4]  = fmaf(w1[k], x, cacc[k + 4]);
        cacc[k + 8]  = fmaf(w2[k], x, cacc[k + 8]);
        cacc[k + 12] = fmaf(w3[k], x, cacc[k + 12]);
      }
    }
#pragma unroll
    for (int k = 0; k < 16; ++k)
      Tbf[((size_t)b * 64 + og * 16 + k) * N + n0 + n] = f2bf(cacc[k]);
  } else {
    // proj path: 4 d-rows per thread -> bf16, n-major store (8B), + sqnorm of rounded
    float r[4];
    bf16x4 hv;
    if (Ap != nullptr) {
      float cacc[4] = {};
#pragma unroll 4
      for (int f = 0; f < FIN; ++f) {
        float x = xS[n][f];
        fx4 w0 = *(const fx4*)&wT[f][og * 4];
#pragma unroll
        for (int k = 0; k < 4; ++k) cacc[k] = fmaf(w0[k], x, cacc[k]);
      }
#pragma unroll
      for (int k = 0; k < 4; ++k) hv[k] = f2bf(cacc[k], &r[k]);
    } else {  // layer 0: scaled + zero-padded
      float inv = 1.f / sigma[0];
#pragma unroll
      for (int k = 0; k < 4; ++k) {
        int d = og * 4 + k;
        float v = (d < F0) ? xS[n][d] * inv : 0.f;
        hv[k] = f2bf(v, &r[k]);
      }
    }
    *(bf16x4*)&projT[((size_t)b * N + n0 + n) * DK + og * 4] = hv;
    float s = 0.f;
#pragma unroll
    for (int k = 0; k < 4; ++k) s = fmaf(r[k], r[k], s);
    sp[og][n] = s;
    __syncthreads();
    if (t < 64) sqnb[(size_t)b * N + n0 + t] = sp[0][t] + sp[1][t] + sp[2][t] + sp[3][t];
  }
}

// ---------------- adjacency+deg+PV via bf16 MFMA; prefetched operands ----------------
__global__ __launch_bounds__(256, 4) void k_adjmsg(const short* __restrict__ projT,  // (B,N,DK)
                                                   const float* __restrict__ sqnb,
                                                   const short* __restrict__ Tbf,
                                                   short* __restrict__ pdmsg,  // (NCH,B,F,N) bf16
                                                   float* __restrict__ pdeg) { // (NCH,B,N)
  constexpr int NCb = N / NCH;      // 512
  constexpr int CPX = NCH * B / 8;  // 2 combos per XCD
  int i = blockIdx.x;
  int xcd = i & 7;
  int j = i >> 3;
  int lc = j / MT;
  int mtile = j - lc * MT;
  int combo = xcd * CPX + lc;  // bijective XCD swizzle
  int ch = combo >> 2;
  int b  = combo & 3;
  int M0 = mtile * 64;
  int n0 = ch * NCb;

  int t = threadIdx.x;
  int w = t >> 6, l = t & 63;
  int l31 = l & 31, lh = l >> 5;
  int mq = w & 1, nq = w >> 1;
  int fq = w & 1, mq2 = w >> 1;

  const short* pbT = projT + (size_t)b * N * DK;
  const short* vb = Tbf + (size_t)b * F * N;   // bf16 W2·V
  const float* sq = sqnb + (size_t)b * N;

  __shared__ __align__(16) short adjT[2][64][68];
  __shared__ __align__(16) short vS[2][64][68];
  __shared__ float sqmS[64];
  __shared__ float degS[2][64];

  // A-fragment: one dwordx4 per lane
  int am = l31 + 32 * mq;
  bf16x8 afrag = *(const bf16x8*)&pbT[(size_t)(M0 + am) * DK + lh * 8];
  if (t < 64) sqmS[t] = sq[M0 + t];
  __syncthreads();
  float sqmr[16];
#pragma unroll
  for (int r = 0; r < 16; ++r)
    sqmr[r] = sqmS[(r & 3) + 8 * (r >> 2) + 4 * lh + 32 * mq];

  f32x16 acc;
#pragma unroll
  for (int r = 0; r < 16; ++r) acc[r] = 0.f;
  float pdm[16];
#pragma unroll
  for (int r = 0; r < 16; ++r) pdm[r] = 0.f;

  // prefetch iteration 0 operands
  int bn = l31 + 32 * nq;
  int fV = t >> 2, nb16 = (t & 3) * 16;
  bf16x8 bfrag = *(const bf16x8*)&pbT[(size_t)(n0 + bn) * DK + lh * 8];
  float sqn_v = sq[n0 + bn];
  bf16x4 vreg[4];
#pragma unroll
  for (int jj = 0; jj < 4; ++jj)
    vreg[jj] = *(const bf16x4*)&vb[(size_t)fV * N + n0 + nb16 + 4 * jj];

  int buf = 0;
  for (int nt = 0; nt < NCb; nt += 64) {
    // commit staged V regs to LDS
#pragma unroll
    for (int jj = 0; jj < 4; ++jj)
      *(bf16x4*)&vS[buf][fV][nb16 + 4 * jj] = vreg[jj];
    // gram via MFMA + exp -> adjT[buf]
    f32x16 gz;
#pragma unroll
    for (int r = 0; r < 16; ++r) gz[r] = 0.f;
    f32x16 g = __builtin_amdgcn_mfma_f32_32x32x16_bf16(afrag, bfrag, gz, 0, 0, 0);
#pragma unroll
    for (int r = 0; r < 16; ++r) {
      int m = (r & 3) + 8 * (r >> 2) + 4 * lh + 32 * mq;
      float dist = fmaxf(sqmr[r] + sqn_v - 2.f * g[r], 0.f);
      float a = __expf(-dist);
      pdm[r] += a;
      adjT[buf][m][bn] = f2bf(a);
    }
    // prefetch next iteration's B-fragment + V tile (hidden under PV MFMAs)
    if (nt + 64 < NCb) {
      bfrag = *(const bf16x8*)&pbT[(size_t)(n0 + nt + 64 + bn) * DK + lh * 8];
      sqn_v = sq[n0 + nt + 64 + bn];
#pragma unroll
      for (int jj = 0; jj < 4; ++jj)
        vreg[jj] = *(const bf16x4*)&vb[(size_t)fV * N + n0 + nt + 64 + nb16 + 4 * jj];
    }
    __syncthreads();  // adjT[buf]/vS[buf] ready
    // PV via MFMA: acc[f][m] += sum_n V[f][n] * adj[m][n]
#pragma unroll
    for (int kk = 0; kk < 4; ++kk) {
      int nb = kk * 16 + lh * 8;
      int fA = l31 + 32 * fq;
      int mB = l31 + 32 * mq2;
      bf16x4 alo = *(const bf16x4*)&vS[buf][fA][nb];
      bf16x4 ahi = *(const bf16x4*)&vS[buf][fA][nb + 4];
      bf16x4 blo = *(const bf16x4*)&adjT[buf][mB][nb];
      bf16x4 bhi = *(const bf16x4*)&adjT[buf][mB][nb + 4];
      bf16x8 af2, bf2;
#pragma unroll
      for (int i2 = 0; i2 < 4; ++i2) {
        af2[i2] = alo[i2]; af2[i2 + 4] = ahi[i2];
        bf2[i2] = blo[i2]; bf2[i2 + 4] = bhi[i2];
      }
      acc = __builtin_amdgcn_mfma_f32_32x32x16_bf16(af2, bf2, acc, 0, 0, 0);
    }
    buf ^= 1;
  }
#pragma unroll
  for (int r = 0; r < 16; ++r) {
    pdm[r] += __shfl_xor(pdm[r], 1);
    pdm[r] += __shfl_xor(pdm[r], 2);
    pdm[r] += __shfl_xor(pdm[r], 4);
    pdm[r] += __shfl_xor(pdm[r], 8);
    pdm[r] += __shfl_xor(pdm[r], 16);
  }
  if (l31 == 0) {
#pragma unroll
    for (int r = 0; r < 16; ++r)
      degS[nq][(r & 3) + 8 * (r >> 2) + 4 * lh + 32 * mq] = pdm[r];
  }
  __syncthreads();
  if (t < 64) {
    float s = degS[0][t] + degS[1][t];
    __builtin_nontemporal_store(s, &pdeg[(size_t)combo * N + M0 + t]);
  }
  short* pdm_g = pdmsg + (size_t)combo * F * N;
  int m_out = l31 + 32 * mq2;
#pragma unroll
  for (int r = 0; r < 16; ++r) {
    int f_r = (r & 3) + 8 * (r >> 2) + 4 * lh + 32 * fq;
    __builtin_nontemporal_store(f2bf(acc[r]), &pdm_g[(size_t)f_r * N + M0 + m_out]);
  }
}

// ---------------- fused chunk-combine + epilogue + full-row stats ----------------
// Block = one output row (b,o); thread handles 2 fx4. ssum/ssq = one entry per row.
__global__ __launch_bounds__(256) void k_ep(const short* __restrict__ pdmsg,  // bf16
                                            const float* __restrict__ pdeg,
                                            const short* __restrict__ Tq,     // (B,2,64,N) bf16
                                            const float* __restrict__ bias,
                                            const float* __restrict__ bres,
                                            short* __restrict__ out,          // (B,64,N) bf16
                                            float* __restrict__ ssum,   // (B*F)
                                            float* __restrict__ ssq) {  // (B*F)
  int row = blockIdx.x;            // b*64 + o
  int o = row & 63, b = row >> 6;
  int t = threadIdx.x;
  float ps = 0.f, pq = 0.f;
  float bi = bias[o], br = bres[o];
#pragma unroll
  for (int h = 0; h < 2; ++h) {
    int c4 = t + h * 256;
    fx4 dm = {0.f, 0.f, 0.f, 0.f};
    fx4 dg = {0.f, 0.f, 0.f, 0.f};
#pragma unroll
    for (int c = 0; c < NCH; ++c) {
      bf16x4 pv = __builtin_nontemporal_load(
          &((const bf16x4*)pdmsg)[(((size_t)c * B + b) * 64 + o) * 512 + c4]);
#pragma unroll
      for (int j = 0; j < 4; ++j) dm[j] += bf2f(pv[j]);
      dg += ((const fx4*)pdeg)[((size_t)c * B + b) * 512 + c4];
    }
    bf16x4 t0v = ((const bf16x4*)Tq)[(((size_t)b * 2 + 0) * 64 + o) * 512 + c4];
    bf16x4 t2v = ((const bf16x4*)Tq)[(((size_t)b * 2 + 1) * 64 + o) * 512 + c4];
    bf16x4 ob;
#pragma unroll
    for (int j = 0; j < 4; ++j) {
      float v = fmaxf(dm[j] + bf2f(t0v[j]) * dg[j] + bi, 0.f) + bf2f(t2v[j]) + br;
      ps += v;
      pq = fmaf(v, v, pq);
      ob[j] = f2bf(v);
    }
    ((bf16x4*)out)[((size_t)b * 64 + o) * 512 + c4] = ob;
  }
#pragma unroll
  for (int off = 1; off < 64; off <<= 1) {
    ps += __shfl_xor(ps, off);
    pq += __shfl_xor(pq, off);
  }
  __shared__ float r1[4], r2[4];
  if ((t & 63) == 0) { r1[t >> 6] = ps; r2[t >> 6] = pq; }
  __syncthreads();
  if (t == 0) {
    ssum[row] = r1[0] + r1[1] + r1[2] + r1[3];
    ssq[row]  = r2[0] + r2[1] + r2[2] + r2[3];
  }
}

// ---------------- readout from ep row sums ----------------
__global__ __launch_bounds__(256) void k_readout(const float* __restrict__ ssum,
                                                 const float* __restrict__ fw,
                                                 const float* __restrict__ fb,
                                                 float* __restrict__ out) {
  int t = threadIdx.x, b = t >> 6, l = t & 63;
  float po = ssum[b * 64 + l] / (float)N;
  float mn = po;
#pragma unroll
  for (int off = 1; off < 64; off <<= 1) mn += __shfl_xor(mn, off);
  mn *= (1.f / 64.f);
  float d = po - mn;
  float var = d * d;
#pragma unroll
  for (int off = 1; off < 64; off <<= 1) var += __shfl_xor(var, off);
  var *= (1.f / 64.f);
  float rs = rsqrtf(var + EPS);
  float lg = d * rs * fw[l];
#pragma unroll
  for (int off = 1; off < 64; off <<= 1) lg += __shfl_xor(lg, off);
  if (l == 0) out[b] = 1.f / (1.f + __expf(-(lg + fb[0])));
}

}  // namespace

extern "C" void kernel_launch(void* const* d_in, const int* in_sizes, int n_in,
                              void* d_out, int out_size, void* d_ws, size_t ws_size,
                              hipStream_t stream) {
  const float* emb_in   = (const float*)d_in[0];
  const float* sigma    = (const float*)d_in[1];
  const float* fst_w    = (const float*)d_in[2];
  const float* fst_b    = (const float*)d_in[3];
  const float* fst_wres = (const float*)d_in[4];
  const float* fst_bres = (const float*)d_in[5];
  const float* adj_proj = (const float*)d_in[6];
  const float* w        = (const float*)d_in[7];
  const float* bw       = (const float*)d_in[8];
  const float* wres     = (const float*)d_in[9];
  const float* bres     = (const float*)d_in[10];
  const float* fcl_w    = (const float*)d_in[11];
  const float* fcl_b    = (const float*)d_in[12];

  float* ws = (float*)d_ws;
  float* pdeg  = ws;  ws += (size_t)NCH * B * N;
  short* pdmsg = (short*)ws;  ws += (size_t)NCH * B * F * N / 2;  // bf16
  short* embA  = (short*)ws;  ws += (size_t)B * F * N / 2;        // bf16
  short* embB  = (short*)ws;  ws += (size_t)B * F * N / 2;        // bf16
  short* Tq    = (short*)ws;  ws += (size_t)B * F * N;            // 2 slices bf16
  short* Tbf   = (short*)ws;  ws += (size_t)B * F * N / 2;
  short* projT = (short*)ws;  ws += (size_t)B * DK * N / 2;
  float* sqnb  = ws;  ws += (size_t)B * N;
  float* ssum  = ws;  ws += (size_t)B * F;
  float* ssq   = ws;  ws += (size_t)B * F;

  constexpr int EPB = B * F;        // 256 blocks; block = one output row
  constexpr int AJB = MT * NCH * B; // 512 blocks

  // ---- layer 0 ----
  k_wx<F0, false, false><<<dim3(N / 64, B, 3), 256, 0, stream>>>(
      emb_in, nullptr, sigma, nullptr, nullptr, fst_w, fst_wres, nullptr,
      Tq, Tbf, projT, sqnb);
  k_adjmsg<<<dim3(AJB), 256, 0, stream>>>(projT, sqnb, Tbf, pdmsg, pdeg);
  k_ep<<<dim3(EPB), 256, 0, stream>>>(pdmsg, pdeg, Tq, fst_b, fst_bres, embA, ssum, ssq);

  // ---- layers 1..2 ----
  const short* src = embA;
  short* dst = embB;
  for (int i = 0; i < 2; ++i) {
    k_wx<F, true, true><<<dim3(N / 64, B, 3), 256, 0, stream>>>(
        nullptr, src, nullptr, ssum, ssq, w + (size_t)i * F * 2 * F,
        wres + (size_t)i * F * F, adj_proj + (size_t)i * DK * F,
        Tq, Tbf, projT, sqnb);
    k_adjmsg<<<dim3(AJB), 256, 0, stream>>>(projT, sqnb, Tbf, pdmsg, pdeg);
    k_ep<<<dim3(EPB), 256, 0, stream>>>(pdmsg, pdeg, Tq, bw + (size_t)i * F,
                                        bres + (size_t)i * F, dst, ssum, ssq);
    short* tmp = (short*)src;
    src = dst;
    dst = tmp;
  }

  k_readout<<<dim3(1), 256, 0, stream>>>(ssum, fcl_w, fcl_b, (float*)d_out);
}